// Round 2
// baseline (3626.068 us; speedup 1.0000x reference)
//
#include <hip/hip_runtime.h>
#include <cstdint>
#include <cstddef>

// ---------------------------------------------------------------------------
// Problem constants
// ---------------------------------------------------------------------------
#define NB      128     // batch
#define RR      300     // rooms
#define EMB     32      // embedding width
#define CENC    33      // 1 + EMB channels after encode
#define MAPD    72      // map H=W

// ---------------------------------------------------------------------------
// 1) Pack room occupancy maps into uint64 bitmasks (bit b = dx*8+dy)
// ---------------------------------------------------------------------------
__global__ __launch_bounds__(256) void build_masks_k(
    const int* __restrict__ rm, unsigned long long* __restrict__ masks)
{
    int r = blockIdx.x * 256 + threadIdx.x;
    if (r >= RR) return;
    unsigned long long m = 0ull;
    #pragma unroll
    for (int b = 0; b < 64; ++b)
        if (rm[r * 64 + b]) m |= (1ull << b);
    masks[r] = m;
}

// ---------------------------------------------------------------------------
// 2) Encode: scatter rooms into chunk-local G[nl][c][y][x]
//    One block per (nl, c); 72x72 fp32 tile in LDS, ds_add_f32 atomics.
// ---------------------------------------------------------------------------
__global__ __launch_bounds__(256) void encode_k(
    const int* __restrict__ X, const unsigned long long* __restrict__ masks,
    const float* __restrict__ emb, float* __restrict__ G, int n0)
{
    __shared__ float tile[MAPD * MAPD];
    const int nl = blockIdx.x;           // chunk-local sample
    const int n  = n0 + nl;              // global sample
    const int c  = blockIdx.y;

    for (int i = threadIdx.x; i < MAPD * MAPD; i += 256) tile[i] = 0.0f;
    __syncthreads();

    const int2* Xp = reinterpret_cast<const int2*>(X);
    for (int r = threadIdx.x; r < RR; r += 256) {
        int2 pos = Xp[n * RR + r];            // (x0, y0)
        float s = (c == 0) ? 1.0f : emb[r * EMB + (c - 1)];
        unsigned long long m = masks[r];
        if (s != 0.0f) {
            while (m) {
                int b = __builtin_ctzll(m);
                m &= (m - 1);
                int dx = b >> 3, dy = b & 7;
                atomicAdd(&tile[(pos.y + dy) * MAPD + (pos.x + dx)], s);
            }
        }
    }
    __syncthreads();

    float* Gn = G + ((size_t)nl * CENC + c) * (MAPD * MAPD);
    for (int i = threadIdx.x; i < MAPD * MAPD; i += 256) Gn[i] = tile[i];
}

// ---------------------------------------------------------------------------
// 3) Weight pre-transpose: w[o][ci][kk] -> wT[ci][kk][o] (coalesced staging)
// ---------------------------------------------------------------------------
__global__ __launch_bounds__(256) void twk(
    const float* __restrict__ w, float* __restrict__ wT,
    int COUT, int CIN, int KK, int total)
{
    int idx = blockIdx.x * 256 + threadIdx.x;
    if (idx >= total) return;
    int kk = idx % KK;
    int t  = idx / KK;
    int ci = t % CIN;
    int o  = t / CIN;
    wT[((size_t)ci * KK + kk) * COUT + o] = w[idx];
}

// ---------------------------------------------------------------------------
// 4) Direct conv + bias + ReLU. Chunk-local batch indices on BOTH in and out.
//    Block: 16x16 spatial tile x 64 output channels, 256 threads.
//    Thread: 4x4 pixels x 4 ocs = 64 accumulators.
// ---------------------------------------------------------------------------
template<int K, int CIN>
__global__ __launch_bounds__(256) void conv_relu_k(
    const float* __restrict__ in, const float* __restrict__ wT,
    const float* __restrict__ bias, float* __restrict__ out,
    int H, int W, int COUT, int ocg_count)
{
    constexpr int TILE = 16;
    constexpr int P    = K / 2;
    constexpr int KK   = K * K;
    constexpr int INW  = TILE + K - 1;   // valid cols per row
    constexpr int INR  = TILE + K - 1;   // rows
    constexpr int LDW  = 20;             // padded row pitch (float4 aligned)

    __shared__ float s_in[INR * LDW];
    __shared__ float s_w[64 * KK];

    const int tid = threadIdx.x;
    const int ps  = tid & 15;            // pixel slot
    const int ocq = tid >> 4;            // 0..15 -> 4 ocs each
    const int sx  = (ps & 3) * 4;
    const int sy  = (ps >> 2) * 4;

    const int nl  = blockIdx.z / ocg_count;   // chunk-local sample
    const int ocg = blockIdx.z % ocg_count;
    const int x0  = blockIdx.x * TILE;
    const int y0  = blockIdx.y * TILE;

    float acc[4][4][4];
    #pragma unroll
    for (int a = 0; a < 4; ++a)
        #pragma unroll
        for (int b = 0; b < 4; ++b)
            #pragma unroll
            for (int j = 0; j < 4; ++j) acc[a][b][j] = 0.0f;

    const float* in_n = in + (size_t)nl * CIN * H * W;

    for (int ci = 0; ci < CIN; ++ci) {
        // stage input tile (zero-padded)
        for (int idx = tid; idx < INR * LDW; idx += 256) {
            int row = idx / LDW, col = idx % LDW;
            float v = 0.0f;
            if (col < INW) {
                int gy = y0 + row - P, gx = x0 + col - P;
                if ((unsigned)gy < (unsigned)H && (unsigned)gx < (unsigned)W)
                    v = in_n[((size_t)ci * H + gy) * W + gx];
            }
            s_in[idx] = v;
        }
        // stage weights for this ci: s_w[kk*64 + o] (coalesced global read)
        for (int idx = tid; idx < 64 * KK; idx += 256) {
            int o  = idx & 63;
            int kk = idx >> 6;
            s_w[idx] = wT[((size_t)ci * KK + kk) * COUT + ocg * 64 + o];
        }
        __syncthreads();

        #pragma unroll
        for (int ky = 0; ky < K; ++ky) {
            float4 wv[K];
            #pragma unroll
            for (int kx = 0; kx < K; ++kx)
                wv[kx] = *reinterpret_cast<const float4*>(
                    &s_w[(ky * K + kx) * 64 + ocq * 4]);
            #pragma unroll
            for (int py = 0; py < 4; ++py) {
                const int base = (sy + py + ky) * LDW + sx;
                float iv[8];
                *reinterpret_cast<float4*>(&iv[0]) =
                    *reinterpret_cast<const float4*>(&s_in[base]);
                *reinterpret_cast<float4*>(&iv[4]) =
                    *reinterpret_cast<const float4*>(&s_in[base + 4]);
                #pragma unroll
                for (int kx = 0; kx < K; ++kx) {
                    #pragma unroll
                    for (int px = 0; px < 4; ++px) {
                        float v = iv[px + kx];
                        acc[py][px][0] += v * wv[kx].x;
                        acc[py][px][1] += v * wv[kx].y;
                        acc[py][px][2] += v * wv[kx].z;
                        acc[py][px][3] += v * wv[kx].w;
                    }
                }
            }
        }
        __syncthreads();
    }

    // epilogue: bias + ReLU + store (chunk-local nl)
    #pragma unroll
    for (int j = 0; j < 4; ++j) {
        int oc = ocg * 64 + ocq * 4 + j;
        float bv = bias[oc];
        #pragma unroll
        for (int py = 0; py < 4; ++py) {
            int y = y0 + sy + py;
            if (y >= H) continue;
            #pragma unroll
            for (int px = 0; px < 4; ++px) {
                int x = x0 + sx + px;
                if (x >= W) continue;
                float v = acc[py][px][j] + bv;
                out[(((size_t)nl * COUT + oc) * H + y) * W + x] =
                    fmaxf(v, 0.0f);
            }
        }
    }
}

// ---------------------------------------------------------------------------
// 5) MaxPool 3x3 stride 2 (VALID), chunk-local
// ---------------------------------------------------------------------------
__global__ __launch_bounds__(256) void maxpool_k(
    const float* __restrict__ in, float* __restrict__ out,
    int H, int W, int HO, int WO, int total)
{
    int idx = blockIdx.x * 256 + threadIdx.x;
    if (idx >= total) return;
    int x = idx % WO;
    int t = idx / WO;
    int y = t % HO;
    t /= HO;                       // t = nl*C + c
    const float* p = in + ((size_t)t * H + y * 2) * W + x * 2;
    float m = -3.402823466e38f;
    #pragma unroll
    for (int dy = 0; dy < 3; ++dy)
        #pragma unroll
        for (int dx = 0; dx < 3; ++dx)
            m = fmaxf(m, p[dy * W + dx]);
    out[idx] = m;
}

// ---------------------------------------------------------------------------
// 6) Global average pool over 8x8 (chunk-local in, global-offset out)
// ---------------------------------------------------------------------------
__global__ __launch_bounds__(256) void gap_k(
    const float* __restrict__ in, float* __restrict__ out, int total)
{
    int idx = blockIdx.x * 256 + threadIdx.x;
    if (idx >= total) return;
    const float4* p = reinterpret_cast<const float4*>(in + (size_t)idx * 64);
    float s = 0.0f;
    #pragma unroll
    for (int i = 0; i < 16; ++i) {
        float4 v = p[i];
        s += v.x + v.y + v.z + v.w;
    }
    out[idx] = s * (1.0f / 64.0f);
}

// ---------------------------------------------------------------------------
// 7) FC: out[n][o] = dot(in[n], w[o]) + b[o], optional ReLU.
//    grid (N, COUT/64), block 256 = 64 outputs x 4 lanes.
// ---------------------------------------------------------------------------
template<int CIN, bool RELU>
__global__ __launch_bounds__(256) void fc_k(
    const float* __restrict__ in, const float* __restrict__ w,
    const float* __restrict__ b, float* __restrict__ out, int COUT)
{
    __shared__ float s_in[CIN];
    const int n = blockIdx.x;
    for (int i = threadIdx.x; i < CIN; i += 256) s_in[i] = in[(size_t)n * CIN + i];
    __syncthreads();

    const int o = blockIdx.y * 64 + (threadIdx.x >> 2);
    const int l = threadIdx.x & 3;
    const float* wr = w + (size_t)o * CIN;
    float acc = 0.0f;
    #pragma unroll 4
    for (int i = l; i < CIN; i += 4) acc += s_in[i] * wr[i];
    acc += __shfl_xor(acc, 1);
    acc += __shfl_xor(acc, 2);
    if (l == 0) {
        float v = acc + b[o];
        out[(size_t)n * COUT + o] = RELU ? fmaxf(v, 0.0f) : v;
    }
}

// ---------------------------------------------------------------------------
// Launch: chunked pipeline over batch; footprint adapted to ws_size.
// Per-sample buffer sizes (floats):
//   G 171,072 | C0 331,776 | P0 78,400 | C1 156,800 | P1 36,992
//   C2 73,984 | P2 16,384
// Overlay: A = max(G,C1,P2)=171,072  B = max(C0,C2)=331,776
//          C = max(P0,P1)=78,400    -> 581,248 floats/sample (2,324,992 B)
// ---------------------------------------------------------------------------
extern "C" void kernel_launch(void* const* d_in, const int* in_sizes, int n_in,
                              void* d_out, int out_size, void* d_ws, size_t ws_size,
                              hipStream_t stream)
{
    const int*   X   = (const int*)d_in[0];
    const int*   rm  = (const int*)d_in[1];
    const float* emb = (const float*)d_in[2];
    const float* cw0 = (const float*)d_in[3];
    const float* cb0 = (const float*)d_in[4];
    const float* cw1 = (const float*)d_in[5];
    const float* cb1 = (const float*)d_in[6];
    const float* cw2 = (const float*)d_in[7];
    const float* cb2 = (const float*)d_in[8];
    const float* fw0 = (const float*)d_in[9];
    const float* fb0 = (const float*)d_in[10];
    const float* fw1 = (const float*)d_in[11];
    const float* fb1 = (const float*)d_in[12];
    const float* fw2 = (const float*)d_in[13];
    const float* fb2 = (const float*)d_in[14];
    float* out = (float*)d_out;

    // ---- fixed-size buffers at the front of ws ----
    char* p = (char*)d_ws;
    auto alloc = [&](size_t bytes) -> char* {
        char* r = p; p += (bytes + 255) & ~(size_t)255; return r;
    };
    float* WT0 = (float*)alloc(33 * 25 * 64 * 4);      // 52,800 f
    float* WT1 = (float*)alloc(64 * 9 * 128 * 4);      // 73,728 f
    float* WT2 = (float*)alloc(128 * 9 * 256 * 4);     // 294,912 f
    unsigned long long* MASKS = (unsigned long long*)alloc(RR * 8);
    float* GAPB = (float*)alloc((size_t)NB * 256 * 4); // 32,768 f
    float* F0   = (float*)alloc((size_t)NB * 512 * 4); // 65,536 f
    float* F1   = (float*)alloc((size_t)NB * 256 * 4); // 32,768 f
    size_t fixed_bytes = (size_t)(p - (char*)d_ws);

    // ---- pick chunk size B: largest power of two fitting in ws_size ----
    const size_t A_FL = 171072, B_FL = 331776, C_FL = 78400;
    const size_t per_sample = (A_FL + B_FL + C_FL) * 4 + 3 * 256; // + align slop
    int B = 32;
    while (B > 1 && fixed_bytes + (size_t)B * per_sample > ws_size) B >>= 1;

    float* bufA = (float*)alloc((size_t)B * A_FL * 4);
    float* bufB = (float*)alloc((size_t)B * B_FL * 4);
    float* bufC = (float*)alloc((size_t)B * C_FL * 4);

    // ---- one-time prep ----
    build_masks_k<<<2, 256, 0, stream>>>(rm, MASKS);
    twk<<<(64 * 33 * 25 + 255) / 256, 256, 0, stream>>>(cw0, WT0, 64, 33, 25, 64 * 33 * 25);
    twk<<<(128 * 64 * 9 + 255) / 256, 256, 0, stream>>>(cw1, WT1, 128, 64, 9, 128 * 64 * 9);
    twk<<<(256 * 128 * 9 + 255) / 256, 256, 0, stream>>>(cw2, WT2, 256, 128, 9, 256 * 128 * 9);

    // ---- chunked pipeline ----
    for (int n0 = 0; n0 < NB; n0 += B) {
        // encode -> A (G: B x 33 x 72 x 72)
        encode_k<<<dim3(B, CENC), 256, 0, stream>>>(X, MASKS, emb, bufA, n0);

        // conv0 (k5, 33->64, 72x72): A -> B
        conv_relu_k<5, 33><<<dim3(5, 5, B), 256, 0, stream>>>(
            bufA, WT0, cb0, bufB, 72, 72, 64, 1);
        // pool0: B -> C (P0: B x 64 x 35 x 35)
        maxpool_k<<<(B * 64 * 35 * 35 + 255) / 256, 256, 0, stream>>>(
            bufB, bufC, 72, 72, 35, 35, B * 64 * 35 * 35);

        // conv1 (k3, 64->128, 35x35): C -> A
        conv_relu_k<3, 64><<<dim3(3, 3, B * 2), 256, 0, stream>>>(
            bufC, WT1, cb1, bufA, 35, 35, 128, 2);
        // pool1: A -> C (P1: B x 128 x 17 x 17)
        maxpool_k<<<(B * 128 * 17 * 17 + 255) / 256, 256, 0, stream>>>(
            bufA, bufC, 35, 35, 17, 17, B * 128 * 17 * 17);

        // conv2 (k3, 128->256, 17x17): C -> B
        conv_relu_k<3, 128><<<dim3(2, 2, B * 4), 256, 0, stream>>>(
            bufC, WT2, cb2, bufB, 17, 17, 256, 4);
        // pool2: B -> A (P2: B x 256 x 8 x 8)
        maxpool_k<<<(B * 256 * 8 * 8 + 255) / 256, 256, 0, stream>>>(
            bufB, bufA, 17, 17, 8, 8, B * 256 * 8 * 8);

        // GAP: A -> GAPB[n0*256 ...]
        gap_k<<<(B * 256 + 255) / 256, 256, 0, stream>>>(
            bufA, GAPB + (size_t)n0 * 256, B * 256);
    }

    // ---- FC stack ----
    fc_k<256, true><<<dim3(NB, 8), 256, 0, stream>>>(GAPB, fw0, fb0, F0, 512);
    fc_k<512, true><<<dim3(NB, 4), 256, 0, stream>>>(F0, fw1, fb1, F1, 256);
    fc_k<256, false><<<dim3(NB, 8), 256, 0, stream>>>(F1, fw2, fb2, out, 512);
}

// Round 3
// 973.316 us; speedup vs baseline: 3.7255x; 3.7255x over previous
//
#include <hip/hip_runtime.h>
#include <hip/hip_bf16.h>
#include <cstdint>
#include <cstddef>

// ---------------------------------------------------------------------------
// Problem constants
// ---------------------------------------------------------------------------
#define NB      128
#define RR      300
#define EMB     32
#define CENC    33

typedef __bf16 bf16x8 __attribute__((ext_vector_type(8)));
typedef float  f32x4  __attribute__((ext_vector_type(4)));
typedef unsigned short ushort8 __attribute__((ext_vector_type(8)));

__device__ __forceinline__ unsigned short f2bf(float f) {
    union { __hip_bfloat16 h; unsigned short u; } c;
    c.h = __float2bfloat16(f);
    return c.u;
}
__device__ __forceinline__ float bf2f(unsigned short u) {
    union { __hip_bfloat16 h; unsigned short u; } c;
    c.u = u;
    return __bfloat162float(c.h);
}

// ---------------------------------------------------------------------------
// 1) Pack room occupancy maps into uint64 bitmasks (bit b = dx*8+dy)
// ---------------------------------------------------------------------------
__global__ __launch_bounds__(256) void build_masks_k(
    const int* __restrict__ rm, unsigned long long* __restrict__ masks)
{
    int r = blockIdx.x * 256 + threadIdx.x;
    if (r >= RR) return;
    unsigned long long m = 0ull;
    #pragma unroll
    for (int b = 0; b < 64; ++b)
        if (rm[r * 64 + b]) m |= (1ull << b);
    masks[r] = m;
}

// ---------------------------------------------------------------------------
// 2) Zero-fill (uint4 grid-stride)
// ---------------------------------------------------------------------------
__global__ __launch_bounds__(256) void fillz_k(uint4* __restrict__ p, size_t n16)
{
    uint4 z = make_uint4(0, 0, 0, 0);
    for (size_t i = blockIdx.x * 256ull + threadIdx.x; i < n16;
         i += (size_t)gridDim.x * 256ull)
        p[i] = z;
}

// ---------------------------------------------------------------------------
// 3) Encode: scatter rooms into padded bf16 G[nl][c][76][76] (interior +2)
// ---------------------------------------------------------------------------
__global__ __launch_bounds__(256) void encode_k(
    const int* __restrict__ X, const unsigned long long* __restrict__ masks,
    const float* __restrict__ emb, unsigned short* __restrict__ G,
    int n0, int sampleStride)
{
    __shared__ float tile[72 * 72];
    const int nl = blockIdx.x;
    const int n  = n0 + nl;
    const int c  = blockIdx.y;

    for (int i = threadIdx.x; i < 72 * 72; i += 256) tile[i] = 0.0f;
    __syncthreads();

    const int2* Xp = reinterpret_cast<const int2*>(X);
    for (int r = threadIdx.x; r < RR; r += 256) {
        int2 pos = Xp[n * RR + r];
        float s = (c == 0) ? 1.0f : emb[r * EMB + (c - 1)];
        unsigned long long m = masks[r];
        if (s != 0.0f) {
            while (m) {
                int b = __builtin_ctzll(m);
                m &= (m - 1);
                int dx = b >> 3, dy = b & 7;
                atomicAdd(&tile[(pos.y + dy) * 72 + (pos.x + dx)], s);
            }
        }
    }
    __syncthreads();

    unsigned short* Gn = G + (size_t)nl * sampleStride + (size_t)c * (76 * 76);
    for (int i = threadIdx.x; i < 72 * 72; i += 256) {
        int y = i / 72, x = i % 72;
        Gn[(y + 2) * 76 + (x + 2)] = f2bf(tile[i]);
    }
}

// ---------------------------------------------------------------------------
// 4) Weight pack: fp32 w[oc][k] -> bf16 wPT[kb][oc][32], K padded w/ zeros
// ---------------------------------------------------------------------------
__global__ __launch_bounds__(256) void wpack_k(
    const float* __restrict__ w, unsigned short* __restrict__ wPT,
    int COUT, int Ktot, int total)
{
    int idx = blockIdx.x * 256 + threadIdx.x;
    if (idx >= total) return;
    int kk = idx & 31;
    int t  = idx >> 5;
    int oc = t % COUT;
    int kb = t / COUT;
    int k  = kb * 32 + kk;
    wPT[idx] = f2bf(k < Ktot ? w[(size_t)oc * Ktot + k] : 0.0f);
}

// ---------------------------------------------------------------------------
// 5) ktab: flat padded-input offset per k-index (k = ci*K*K + ky*K + kx)
// ---------------------------------------------------------------------------
__global__ __launch_bounds__(256) void ktab_k(
    int* __restrict__ kt, int Ktot, int Kpad, int K, int Wp, int HpWp)
{
    int k = blockIdx.x * 256 + threadIdx.x;
    if (k >= Kpad) return;
    int v = 0;
    if (k < Ktot) {
        int KK = K * K;
        int ci = k / KK;
        int r  = k - ci * KK;
        int ky = r / K;
        int kx = r - ky * K;
        v = ci * HpWp + ky * Wp + kx;
    }
    kt[k] = v;
}

// ---------------------------------------------------------------------------
// 6) Implicit-GEMM conv + bias + ReLU, bf16 MFMA 16x16x32.
//    Block: 64 positions x 64 output channels, 256 threads (4 waves).
//    A: im2col gather (padded input, ktab offsets) -> LDS [64][32] (pitch 40)
//    B: packed weights -> LDS [64 oc][32]           (pitch 40)
//    Epilogue: LDS transpose (pitch 66) -> coalesced 4B stores.
// ---------------------------------------------------------------------------
__global__ __launch_bounds__(256) void conv_mfma_k(
    const unsigned short* __restrict__ inP,   // [B][CIN][Hp][Wp] bf16, halo=0
    const unsigned short* __restrict__ wPT,   // [ksteps][COUT][32] bf16
    const int* __restrict__ ktab,             // [ksteps*32]
    const float* __restrict__ bias,
    unsigned short* __restrict__ out,         // [B][COUT][Mpad] bf16
    int W, int Wp, int Mtot, int Mpad,
    int inSS, int outSS, int ksteps, int COUT)
{
    __shared__ unsigned short s_ab[2 * 64 * 40];   // A then B (pitch 40)
    __shared__ int s_kt[1152];

    unsigned short* s_a = s_ab;
    unsigned short* s_b = s_ab + 64 * 40;

    const int tid  = threadIdx.x;
    const int mb   = blockIdx.x;
    const int ocb  = blockIdx.y;
    const int nl   = blockIdx.z;

    // load ktab to LDS
    const int ktn = ksteps * 32;
    for (int i = tid; i < ktn; i += 256) s_kt[i] = ktab[i];

    // staging roles
    const int row = tid >> 2;        // 0..63 (A: position row, B: oc row)
    const int kc  = tid & 3;         // 8-elem chunk within 32

    int p  = mb * 64 + row;
    int pc = p < Mtot ? p : (Mtot - 1);
    int y  = pc / W;
    int x  = pc - y * W;
    const unsigned short* in_n = inP + (size_t)nl * inSS;
    const int pbase = y * Wp + x;

    const unsigned short* wsrc =
        wPT + ((size_t)ocb * 64) * 32 + (size_t)tid * 8;   // + kb*COUT*32 per step

    // fragment roles
    const int lane = tid & 63;
    const int wv   = tid >> 6;
    const int frow = lane & 15;
    const int fq   = lane >> 4;
    const int aoff = (wv * 16 + frow) * 40 + fq * 8;

    f32x4 acc[4];
    #pragma unroll
    for (int i = 0; i < 4; ++i) acc[i] = (f32x4){0.f, 0.f, 0.f, 0.f};

    __syncthreads();   // s_kt ready

    for (int kb = 0; kb < ksteps; ++kb) {
        // --- stage A (gather) ---
        const int* ktp = &s_kt[kb * 32 + kc * 8];
        ushort8 av;
        #pragma unroll
        for (int j = 0; j < 8; ++j) av[j] = in_n[pbase + ktp[j]];
        *reinterpret_cast<ushort8*>(&s_a[row * 40 + kc * 8]) = av;
        // --- stage B (contiguous) ---
        ushort8 bv = *reinterpret_cast<const ushort8*>(wsrc + (size_t)kb * COUT * 32);
        *reinterpret_cast<ushort8*>(&s_b[row * 40 + kc * 8]) = bv;
        __syncthreads();

        bf16x8 af = *reinterpret_cast<const bf16x8*>(&s_a[aoff]);
        #pragma unroll
        for (int ng = 0; ng < 4; ++ng) {
            bf16x8 bf = *reinterpret_cast<const bf16x8*>(
                &s_b[(ng * 16 + frow) * 40 + fq * 8]);
            acc[ng] = __builtin_amdgcn_mfma_f32_16x16x32_bf16(af, bf, acc[ng], 0, 0, 0);
        }
        __syncthreads();
    }

    // --- epilogue: bias+ReLU, transpose via LDS, coalesced store ---
    unsigned short* s_c = s_ab;   // [64 p][66] pitch
    #pragma unroll
    for (int ng = 0; ng < 4; ++ng) {
        float bv = bias[ocb * 64 + ng * 16 + frow];
        #pragma unroll
        for (int r = 0; r < 4; ++r) {
            float v = acc[ng][r] + bv;
            v = fmaxf(v, 0.0f);
            s_c[(wv * 16 + fq * 4 + r) * 66 + ng * 16 + frow] = f2bf(v);
        }
    }
    __syncthreads();

    unsigned short* out_n = out + (size_t)nl * outSS;
    const int oc0 = tid >> 5;          // 0..7
    const int px  = (tid & 31) * 2;
    #pragma unroll
    for (int pass = 0; pass < 8; ++pass) {
        int oc_l = pass * 8 + oc0;
        int pp   = mb * 64 + px;
        if (pp < Mtot) {
            unsigned lo = s_c[px * 66 + oc_l];
            unsigned hi = s_c[(px + 1) * 66 + oc_l];
            *reinterpret_cast<unsigned*>(
                &out_n[(size_t)(ocb * 64 + oc_l) * Mpad + pp]) = lo | (hi << 16);
        }
    }
}

// ---------------------------------------------------------------------------
// 7) MaxPool 3x3 stride 2 (VALID), bf16 in/out, writes padded interior
// ---------------------------------------------------------------------------
__global__ __launch_bounds__(256) void maxpool_bf_k(
    const unsigned short* __restrict__ in, unsigned short* __restrict__ out,
    int C, int H, int W, int chS, int inSS,
    int HO, int WO, int Wpo, int po, int outChS, int outSS, int total)
{
    int idx = blockIdx.x * 256 + threadIdx.x;
    if (idx >= total) return;
    int x = idx % WO;
    int t = idx / WO;
    int y = t % HO;
    t /= HO;
    int c  = t % C;
    int nl = t / C;
    const unsigned short* p =
        in + (size_t)nl * inSS + (size_t)c * chS + (y * 2) * W + x * 2;
    float m = -3.402823466e38f;
    #pragma unroll
    for (int dy = 0; dy < 3; ++dy)
        #pragma unroll
        for (int dx = 0; dx < 3; ++dx)
            m = fmaxf(m, bf2f(p[dy * W + dx]));
    out[(size_t)nl * outSS + (size_t)c * outChS + (y + po) * Wpo + (x + po)] =
        f2bf(m);
}

// ---------------------------------------------------------------------------
// 8) Global average pool over 8x8 (bf16 in -> fp32 out)
// ---------------------------------------------------------------------------
__global__ __launch_bounds__(256) void gap_bf_k(
    const unsigned short* __restrict__ in, float* __restrict__ out,
    int inSS, int total)
{
    int idx = blockIdx.x * 256 + threadIdx.x;
    if (idx >= total) return;
    int c  = idx & 255;
    int nl = idx >> 8;
    const unsigned short* p = in + (size_t)nl * inSS + (size_t)c * 64;
    float s = 0.0f;
    #pragma unroll
    for (int i = 0; i < 64; ++i) s += bf2f(p[i]);
    out[idx] = s * (1.0f / 64.0f);
}

// ---------------------------------------------------------------------------
// 9) FC (fp32): out[n][o] = dot(in[n], w[o]) + b[o], optional ReLU
// ---------------------------------------------------------------------------
template<int CIN, bool RELU>
__global__ __launch_bounds__(256) void fc_k(
    const float* __restrict__ in, const float* __restrict__ w,
    const float* __restrict__ b, float* __restrict__ out, int COUT)
{
    __shared__ float s_in[CIN];
    const int n = blockIdx.x;
    for (int i = threadIdx.x; i < CIN; i += 256) s_in[i] = in[(size_t)n * CIN + i];
    __syncthreads();

    const int o = blockIdx.y * 64 + (threadIdx.x >> 2);
    const int l = threadIdx.x & 3;
    const float* wr = w + (size_t)o * CIN;
    float acc = 0.0f;
    #pragma unroll 4
    for (int i = l; i < CIN; i += 4) acc += s_in[i] * wr[i];
    acc += __shfl_xor(acc, 1);
    acc += __shfl_xor(acc, 2);
    if (l == 0) {
        float v = acc + b[o];
        out[(size_t)n * COUT + o] = RELU ? fmaxf(v, 0.0f) : v;
    }
}

// ---------------------------------------------------------------------------
// Launch
// Per-sample bf16 buffer sizes (ushorts):
//   A: G 33*76*76=190,608  (C1 128*1226=156,928 and P2 256*64=16,384 overlay)
//   B: C0 64*5184=331,776  (C2 256*290=74,240 overlays)
//   C: P0p 64*37*37=87,616 + P1p 128*19*19=46,208 = 133,824 (disjoint)
// ---------------------------------------------------------------------------
extern "C" void kernel_launch(void* const* d_in, const int* in_sizes, int n_in,
                              void* d_out, int out_size, void* d_ws, size_t ws_size,
                              hipStream_t stream)
{
    const int*   X   = (const int*)d_in[0];
    const int*   rm  = (const int*)d_in[1];
    const float* emb = (const float*)d_in[2];
    const float* cw0 = (const float*)d_in[3];
    const float* cb0 = (const float*)d_in[4];
    const float* cw1 = (const float*)d_in[5];
    const float* cb1 = (const float*)d_in[6];
    const float* cw2 = (const float*)d_in[7];
    const float* cb2 = (const float*)d_in[8];
    const float* fw0 = (const float*)d_in[9];
    const float* fb0 = (const float*)d_in[10];
    const float* fw1 = (const float*)d_in[11];
    const float* fb1 = (const float*)d_in[12];
    const float* fw2 = (const float*)d_in[13];
    const float* fb2 = (const float*)d_in[14];
    float* out = (float*)d_out;

    char* p = (char*)d_ws;
    auto alloc = [&](size_t bytes) -> char* {
        char* r = p; p += (bytes + 255) & ~(size_t)255; return r;
    };
    // conv K-dims: 33*25=825 -> 26 steps; 64*9=576 -> 18; 128*9=1152 -> 36
    unsigned short* WP0 = (unsigned short*)alloc((size_t)26 * 64 * 32 * 2);
    unsigned short* WP1 = (unsigned short*)alloc((size_t)18 * 128 * 32 * 2);
    unsigned short* WP2 = (unsigned short*)alloc((size_t)36 * 256 * 32 * 2);
    int* KT0 = (int*)alloc(26 * 32 * 4);
    int* KT1 = (int*)alloc(18 * 32 * 4);
    int* KT2 = (int*)alloc(36 * 32 * 4);
    unsigned long long* MASKS = (unsigned long long*)alloc(RR * 8);
    float* GAPB = (float*)alloc((size_t)NB * 256 * 4);
    float* F0   = (float*)alloc((size_t)NB * 512 * 4);
    float* F1   = (float*)alloc((size_t)NB * 256 * 4);
    size_t fixed_bytes = (size_t)(p - (char*)d_ws);

    const size_t A_FL = 190608, B_FL = 331776, C_FL = 133824;   // ushorts
    const size_t per_sample = (A_FL + B_FL + C_FL) * 2 + 3 * 256;
    int Bc = 32;
    while (Bc > 1 && fixed_bytes + (size_t)Bc * per_sample > ws_size) Bc >>= 1;

    unsigned short* bufA = (unsigned short*)alloc((size_t)Bc * A_FL * 2);
    unsigned short* bufB = (unsigned short*)alloc((size_t)Bc * B_FL * 2);
    unsigned short* bufC = (unsigned short*)alloc((size_t)Bc * C_FL * 2);

    // ---- one-time prep ----
    build_masks_k<<<2, 256, 0, stream>>>(rm, MASKS);
    wpack_k<<<(26 * 64 * 32 + 255) / 256, 256, 0, stream>>>(cw0, WP0, 64, 825, 26 * 64 * 32);
    wpack_k<<<(18 * 128 * 32 + 255) / 256, 256, 0, stream>>>(cw1, WP1, 128, 576, 18 * 128 * 32);
    wpack_k<<<(36 * 256 * 32 + 255) / 256, 256, 0, stream>>>(cw2, WP2, 256, 1152, 36 * 256 * 32);
    ktab_k<<<(26 * 32 + 255) / 256, 256, 0, stream>>>(KT0, 825, 26 * 32, 5, 76, 76 * 76);
    ktab_k<<<(18 * 32 + 255) / 256, 256, 0, stream>>>(KT1, 576, 18 * 32, 3, 37, 37 * 37);
    ktab_k<<<(36 * 32 + 255) / 256, 256, 0, stream>>>(KT2, 1152, 36 * 32, 3, 19, 19 * 19);

    // ---- chunked pipeline ----
    for (int n0 = 0; n0 < NB; n0 += Bc) {
        // zero padded buffers (halos)
        fillz_k<<<1024, 256, 0, stream>>>((uint4*)bufA, (size_t)Bc * A_FL * 2 / 16);
        fillz_k<<<1024, 256, 0, stream>>>((uint4*)bufC, (size_t)Bc * C_FL * 2 / 16);

        // encode -> A (G: Bc x 33 x 76 x 76, interior +2)
        encode_k<<<dim3(Bc, CENC), 256, 0, stream>>>(X, MASKS, emb, bufA, n0, (int)A_FL);

        // conv0: A -> B   (M=5184, Mpad=5184, 81 mblocks, 1 ocblock)
        conv_mfma_k<<<dim3(81, 1, Bc), 256, 0, stream>>>(
            bufA, WP0, KT0, cb0, bufB, 72, 76, 5184, 5184,
            (int)A_FL, (int)B_FL, 26, 64);
        // pool0: B -> C(P0p @ +1, pitch 37)
        maxpool_bf_k<<<(Bc * 64 * 35 * 35 + 255) / 256, 256, 0, stream>>>(
            bufB, bufC, 64, 72, 72, 5184, (int)B_FL,
            35, 35, 37, 1, 37 * 37, (int)C_FL, Bc * 64 * 35 * 35);

        // conv1: C -> A   (M=1225, Mpad=1226, 20 mblocks, 2 ocblocks)
        conv_mfma_k<<<dim3(20, 2, Bc), 256, 0, stream>>>(
            bufC, WP1, KT1, cb1, bufA, 35, 37, 1225, 1226,
            (int)C_FL, (int)A_FL, 18, 128);
        // pool1: A -> C(P1p @ offset 87616, +1, pitch 19)
        maxpool_bf_k<<<(Bc * 128 * 17 * 17 + 255) / 256, 256, 0, stream>>>(
            bufA, bufC + 87616, 128, 35, 35, 1226, (int)A_FL,
            17, 17, 19, 1, 19 * 19, (int)C_FL, Bc * 128 * 17 * 17);

        // conv2: C -> B   (M=289, Mpad=290, 5 mblocks, 4 ocblocks)
        conv_mfma_k<<<dim3(5, 4, Bc), 256, 0, stream>>>(
            bufC + 87616, WP2, KT2, cb2, bufB, 17, 19, 289, 290,
            (int)C_FL, (int)B_FL, 36, 256);
        // pool2: B -> A (P2: 256 x 8 x 8, unpadded)
        maxpool_bf_k<<<(Bc * 256 * 8 * 8 + 255) / 256, 256, 0, stream>>>(
            bufB, bufA, 256, 17, 17, 290, (int)B_FL,
            8, 8, 8, 0, 64, (int)A_FL, Bc * 256 * 8 * 8);

        // GAP: A -> GAPB[n0*256..]
        gap_bf_k<<<(Bc * 256 + 255) / 256, 256, 0, stream>>>(
            bufA, GAPB + (size_t)n0 * 256, (int)A_FL, Bc * 256);
    }

    // ---- FC stack (fp32) ----
    fc_k<256, true><<<dim3(NB, 8), 256, 0, stream>>>(GAPB, fw0, fb0, F0, 512);
    fc_k<512, true><<<dim3(NB, 4), 256, 0, stream>>>(F0, fw1, fb1, F1, 256);
    fc_k<256, false><<<dim3(NB, 8), 256, 0, stream>>>(F1, fw2, fb2, out, 512);
}